// Round 8
// baseline (716.076 us; speedup 1.0000x reference)
//
#include <hip/hip_runtime.h>

#define EPSF 1e-5f

typedef _Float16 h8    __attribute__((ext_vector_type(8)));
typedef float    f32x4 __attribute__((ext_vector_type(4)));

__device__ __forceinline__ float fsig(float x){ return 1.0f/(1.0f+__expf(-x)); }
__device__ __forceinline__ float ftanh(float x){
  float e = __expf(2.f*x);
  float r = (e-1.f)/(e+1.f);
  return (x > 15.f) ? 1.f : ((x < -15.f) ? -1.f : r);
}
// pack two f32 -> f16x2
__device__ __forceinline__ int pkf(float lo, float hi){
  return __builtin_bit_cast(int, __builtin_amdgcn_cvt_pkrtz(lo, hi));
}
// build a B-fragment int4 (8 consecutive K-values of one column's weights)
__device__ __forceinline__ int4 mk4(const float* p){
  return make_int4(pkf(p[0],p[1]),pkf(p[2],p[3]),pkf(p[4],p[5]),pkf(p[6],p[7]));
}
#define MFMA(A,B,C) __builtin_amdgcn_mfma_f32_16x16x32_f16( \
    __builtin_bit_cast(h8,(A)), __builtin_bit_cast(h8,(B)), (C), 0,0,0)
// light barrier: drain LDS, leave global loads/stores in flight
#define BAR() do{ asm volatile("s_waitcnt lgkmcnt(0)" ::: "memory"); __builtin_amdgcn_s_barrier(); }while(0)

// ---------------------------------------------------------------------------
// Kernel 1: msum[t] = sum_{b,n} masks[b,t,n] + EPS   (one block per t)
// ---------------------------------------------------------------------------
__global__ void msum_kernel(const float* __restrict__ masks, float* __restrict__ msum){
  const int t   = blockIdx.x;
  const int tid = threadIdx.x;
  const int b0  = tid >> 3;
  const int n4  = (tid & 7) << 2;
  float s = 0.f;
  #pragma unroll 4
  for (int i = 0; i < 32; ++i) {
    const int b = b0 + (i << 5);
    const float4 v = *reinterpret_cast<const float4*>(masks + ((size_t)b*256 + t)*32 + n4);
    s += v.x + v.y + v.z + v.w;
  }
  __shared__ float red[256];
  red[tid] = s; __syncthreads();
  for (int off = 128; off > 0; off >>= 1) {
    if (tid < off) red[tid] += red[tid + off];
    __syncthreads();
  }
  if (tid == 0) msum[t] = red[0] + EPSF;
}

// ---------------------------------------------------------------------------
// Kernel 2: persistent RNN. 256 blocks x 512 threads, 4 batch elems / block.
// 6-phase all-MFMA pipeline; ALL weights live in VGPR B-fragments (zero LDS
// weight traffic, zero shuffles). Waves 0-3: chain transforms (pair-space,
// elem=wv) + small GEMMs (C,B | Da,Dz). Waves 4-7: gate GEMM, acc held in
// regs across phases (hh early, ih late), wave-uniform activation (i/f/g/o).
// gamma_h GEMM for t+1 runs in step t (d prefetched 2 deep).
// ---------------------------------------------------------------------------
__global__ __launch_bounds__(512, 2) void rits_kernel(
  const float* __restrict__ values, const float* __restrict__ masks,
  const float* __restrict__ deltas, const float* __restrict__ labels,
  const float* __restrict__ is_train,
  const float* __restrict__ td_h_W, const float* __restrict__ td_h_b,
  const float* __restrict__ td_x_W, const float* __restrict__ td_x_b,
  const float* __restrict__ hist_W, const float* __restrict__ hist_b,
  const float* __restrict__ feat_W, const float* __restrict__ feat_b,
  const float* __restrict__ wc_W,  const float* __restrict__ wc_b,
  const float* __restrict__ W_ih,  const float* __restrict__ W_hh,
  const float* __restrict__ b_ih,  const float* __restrict__ b_hh,
  const float* __restrict__ out_W, const float* __restrict__ out_b,
  const float* __restrict__ msum,
  float* __restrict__ xl_acc, float* __restrict__ bce_acc,
  float* __restrict__ predictions, float* __restrict__ imps)
{
  // A-fragment staging (packed f16 pairs); rows padded to 36 ints (144B,
  // 16B-aligned, rows land on distinct bank quads)
  __shared__ __align__(16) int A_B[4][36];   // dw(t+1) words 0..15
  __shared__ __align__(16) int A_C[4][36];   // hw(t) words 0..31
  __shared__ __align__(16) int A_Dz[4][36];  // x_c(t) words 0..15
  __shared__ __align__(16) int A_Da[4][36];  // [gx(t) 0..15 | m(t) 16..31]
  __shared__ __align__(16) int A_E[4][36];   // [cc(t) 0..15 | m(t) 16..31]
  __shared__ __align__(16) float sB[4][64];  // td_h GEMM out (for t+1)
  __shared__ __align__(16) float sC[4][32];  // x_h
  __shared__ __align__(16) float sDz[4][32]; // z
  __shared__ __align__(16) float sDa[4][32]; // alpha
  __shared__ __align__(16) float gp[4][256]; // ACTIVATED gates
  __shared__ float msum_l[256];              // 1/msum[t]

  const int tid = threadIdx.x;
  const int b   = blockIdx.x;
  const int wv  = tid >> 6;          // 0..7
  const int l   = tid & 63;
  const int c16 = l & 15;
  const int kg  = l >> 4;
  const int arow= l & 3;             // A-row clamp (rows 4-15 unused)
  const bool ch = (wv < 4);

  // ---- stage msum; zero gp (so F at t=0 yields c=h=0) and sB ----
  if (tid < 256) msum_l[tid] = 1.f / msum[tid];
  { float* g = (float*)gp; g[tid] = 0.f; g[tid+512] = 0.f; }
  if (tid < 256) ((float*)sB)[tid] = 0.f;

  // ---- per-wave VGPR B-fragments ----
  int4 fC0, fC1, fB0, fB1, fDa0, fDa1, fDz;
  int4 fEh[4][2], fEi[4][2];
  f32x4 accE[4];
  float cbias=0.f, dabias=0.f, dzbias=0.f, bb0=0.f, bb1=0.f;
  float ebias[4] = {0.f,0.f,0.f,0.f};
  if (wv < 2){
    const int n = (wv<<4) | c16;                 // hist col
    fC0 = mk4(hist_W + n*64 + kg*8);
    fC1 = mk4(hist_W + n*64 + 32 + kg*8);
    cbias = hist_b[n];
    const int j0 = (wv<<5) | c16;                // td_h cols (2 tiles)
    fB0 = mk4(td_h_W + j0*32 + kg*8);
    fB1 = mk4(td_h_W + (j0+16)*32 + kg*8);
    bb0 = td_h_b[j0]; bb1 = td_h_b[j0+16];
  } else if (wv < 4){
    const int n = ((wv-2)<<4) | c16;             // wc / feat col
    fDa0 = mk4(wc_W + n*64 + kg*8);
    fDa1 = mk4(wc_W + n*64 + 32 + kg*8);
    dabias = wc_b[n];
    float v[8];
    #pragma unroll
    for (int k = 0; k < 8; ++k){ const int c = kg*8+k; v[k] = (c==n) ? 0.f : feat_W[n*32+c]; }
    fDz = make_int4(pkf(v[0],v[1]),pkf(v[2],v[3]),pkf(v[4],v[5]),pkf(v[6],v[7]));
    dzbias = feat_b[n];
  } else {
    const int wq = wv - 4;                       // gate block: 0=i 1=f 2=g 3=o
    #pragma unroll
    for (int nt = 0; nt < 4; ++nt){
      const int col = wq*64 + nt*16 + c16;
      fEh[nt][0] = mk4(W_hh + (size_t)col*64 + kg*8);
      fEh[nt][1] = mk4(W_hh + (size_t)col*64 + 32 + kg*8);
      fEi[nt][0] = mk4(W_ih + (size_t)col*64 + kg*8);
      fEi[nt][1] = mk4(W_ih + (size_t)col*64 + 32 + kg*8);
      ebias[nt]  = b_ih[col] + b_hh[col];
    }
  }

  // ---- chain registers (pair-space: lane l<16 owns features 2l,2l+1;
  //      lane l<32 owns hidden rows 2l,2l+1) ----
  const int b2 = (b<<2) | (wv & 3);
  float tdd0=0.f,tdd1=0.f,tdb0=0.f,tdb1=0.f, ow0=0.f,ow1=0.f;
  float xc0=0.f,xc1=0.f,mc0=0.f,mc1=0.f;     // cur  (t)
  float xo0=0.f,xo1=0.f,mo0=0.f,mo1=0.f;     // old  (t, for T3)
  float lx0=0.f,lx1=0.f,lm0=0.f,lm1=0.f,ld0=0.f,ld1=0.f; // inbound (t+1)
  float h0=0.f,h1=0.f,cs0=0.f,cs1=0.f;
  float xh0=0.f,xh1=0.f, la=0.f;
  if (ch){
    if (l < 32){ const float2 o = *(const float2*)(out_W + 2*l); ow0=o.x; ow1=o.y; }
    if (l < 16){
      tdd0 = td_x_W[(2*l)*33];   tdd1 = td_x_W[(2*l+1)*33];
      tdb0 = td_x_b[2*l];        tdb1 = td_x_b[2*l+1];
      const size_t base = (size_t)b2*8192 + 2*l;
      const float2 xv = *(const float2*)(values + base);
      const float2 mv = *(const float2*)(masks  + base);
      const float2 dv = *(const float2*)(deltas + base);
      xc0=xv.x; xc1=xv.y; mc0=mv.x; mc1=mv.y;
      // A_Da(0): gx(0)|m(0)
      const float g0 = __expf(-fmaxf(fmaf(dv.x,tdd0,tdb0),0.f));
      const float g1 = __expf(-fmaxf(fmaf(dv.y,tdd1,tdb1),0.f));
      A_Da[wv][l]    = pkf(g0,g1);
      A_Da[wv][16+l] = pkf(mc0,mc1);
      // prime inbound with t=1
      const float2 xn = *(const float2*)(values + base + 32);
      const float2 mn = *(const float2*)(masks  + base + 32);
      const float2 dn = *(const float2*)(deltas + base + 32);
      lx0=xn.x; lx1=xn.y; lm0=mn.x; lm1=mn.y; ld0=dn.x; ld1=dn.y;
    }
  }
  __syncthreads();

  for (int t = 0; t < 256; ++t){
    // ---- PH1: F(t-1) then T1: h *= gamma_h(t); write hw words ----
    if (ch && l < 32){
      const float2 gi = *(const float2*)&gp[wv][2*l];
      const float2 gf = *(const float2*)&gp[wv][64+2*l];
      const float2 gg = *(const float2*)&gp[wv][128+2*l];
      const float2 go = *(const float2*)&gp[wv][192+2*l];
      cs0 = gf.x*cs0 + gi.x*gg.x;   cs1 = gf.y*cs1 + gi.y*gg.y;
      h0  = go.x*ftanh(cs0);        h1  = go.y*ftanh(cs1);
      const float2 sb = *(const float2*)&sB[wv][2*l];
      h0 *= __expf(-fmaxf(sb.x,0.f));
      h1 *= __expf(-fmaxf(sb.y,0.f));
      A_C[wv][l] = pkf(h0,h1);
    }
    BAR();
    // ---- PH2: C-GEMM (w0,1) | Da-GEMM (w2,3) | E-hh (w4-7, acc held) ----
    if (wv < 2){
      const int4 a0 = *(const int4*)&A_C[arow][kg*4];
      const int4 a1 = *(const int4*)&A_C[arow][16+kg*4];
      f32x4 acc = {cbias,cbias,cbias,cbias};
      acc = MFMA(a0,fC0,acc); acc = MFMA(a1,fC1,acc);
      if (l < 16){
        #pragma unroll
        for (int e = 0; e < 4; ++e) sC[e][(wv<<4)|c16] = acc[e];
      }
    } else if (wv < 4){
      const int4 a0 = *(const int4*)&A_Da[arow][kg*4];
      const int4 a1 = *(const int4*)&A_Da[arow][16+kg*4];
      f32x4 acc = {dabias,dabias,dabias,dabias};
      acc = MFMA(a0,fDa0,acc); acc = MFMA(a1,fDa1,acc);
      if (l < 16){
        #pragma unroll
        for (int e = 0; e < 4; ++e) sDa[e][((wv-2)<<4)|c16] = acc[e];
      }
    } else {
      const int4 a0 = *(const int4*)&A_C[arow][kg*4];
      const int4 a1 = *(const int4*)&A_C[arow][16+kg*4];
      #pragma unroll
      for (int nt = 0; nt < 4; ++nt){
        accE[nt] = (f32x4){ebias[nt],ebias[nt],ebias[nt],ebias[nt]};
        accE[nt] = MFMA(a0,fEh[nt][0],accE[nt]);
        accE[nt] = MFMA(a1,fEh[nt][1],accE[nt]);
      }
    }
    BAR();
    // ---- PH3: T2 (x_h -> x_c, loss1) + T0'(t+1) + rotate + prefetch(t+2) ----
    if (ch && l < 16){
      const float2 sc = *(const float2*)&sC[wv][2*l];
      xh0 = sc.x; xh1 = sc.y;
      la += (fabsf(xc0-xh0)*mc0 + fabsf(xc1-xh1)*mc1) * msum_l[t];
      const float q0 = mc0*xc0 + (1.f-mc0)*xh0;
      const float q1 = mc1*xc1 + (1.f-mc1)*xh1;
      A_Dz[wv][l] = pkf(q0,q1);
      // T0'(t+1): gx, dw, m words from inbound regs
      const float g0 = __expf(-fmaxf(fmaf(ld0,tdd0,tdb0),0.f));
      const float g1 = __expf(-fmaxf(fmaf(ld1,tdd1,tdb1),0.f));
      A_B[wv][l]     = pkf(ld0,ld1);
      A_Da[wv][l]    = pkf(g0,g1);
      A_Da[wv][16+l] = pkf(lm0,lm1);
      // rotate and issue loads for t+2
      xo0=xc0; xo1=xc1; mo0=mc0; mo1=mc1;
      xc0=lx0; xc1=lx1; mc0=lm0; mc1=lm1;
      if (t < 254){
        const size_t base = (size_t)b2*8192 + (size_t)(t+2)*32 + 2*l;
        const float2 xn = *(const float2*)(values + base);
        const float2 mn = *(const float2*)(masks  + base);
        const float2 dn = *(const float2*)(deltas + base);
        lx0=xn.x; lx1=xn.y; lm0=mn.x; lm1=mn.y; ld0=dn.x; ld1=dn.y;
      }
    }
    BAR();
    // ---- PH4: B-GEMM(t+1) (w0,1) | Dz-GEMM (w2,3) ----
    if (wv < 2){
      const int4 a = *(const int4*)&A_B[arow][kg*4];
      f32x4 p = {bb0,bb0,bb0,bb0};
      p = MFMA(a,fB0,p);
      f32x4 q = {bb1,bb1,bb1,bb1};
      q = MFMA(a,fB1,q);
      if (l < 16){
        #pragma unroll
        for (int e = 0; e < 4; ++e){
          sB[e][(wv<<5)|c16]    = p[e];
          sB[e][(wv<<5)+16+c16] = q[e];
        }
      }
    } else if (wv < 4){
      const int4 a = *(const int4*)&A_Dz[arow][kg*4];
      f32x4 acc = {dzbias,dzbias,dzbias,dzbias};
      acc = MFMA(a,fDz,acc);
      if (l < 16){
        #pragma unroll
        for (int e = 0; e < 4; ++e) sDz[e][((wv-2)<<4)|c16] = acc[e];
      }
    }
    BAR();
    // ---- PH5: T3 (c_h, loss23, cc, imps; write cc|m words for E-ih) ----
    if (ch && l < 16){
      const float2 z2 = *(const float2*)&sDz[wv][2*l];
      const float2 a2 = *(const float2*)&sDa[wv][2*l];
      const float c0 = a2.x*z2.x + (1.f-a2.x)*xh0;
      const float c1 = a2.y*z2.y + (1.f-a2.y)*xh1;
      la += ((fabsf(xo0-z2.x)+fabsf(xo0-c0))*mo0
           + (fabsf(xo1-z2.y)+fabsf(xo1-c1))*mo1) * msum_l[t];
      const float cc0 = mo0*xo0 + (1.f-mo0)*c0;
      const float cc1 = mo1*xo1 + (1.f-mo1)*c1;
      A_E[wv][l]    = pkf(cc0,cc1);
      A_E[wv][16+l] = pkf(mo0,mo1);
      *(float2*)(imps + (size_t)b2*8192 + (size_t)t*32 + 2*l) = make_float2(cc0,cc1);
    }
    BAR();
    // ---- PH6: E-ih add into held acc; activate (wave-uniform); store gp ----
    if (wv >= 4){
      const int wq = wv - 4;
      const int4 a0 = *(const int4*)&A_E[arow][kg*4];
      const int4 a1 = *(const int4*)&A_E[arow][16+kg*4];
      #pragma unroll
      for (int nt = 0; nt < 4; ++nt){
        accE[nt] = MFMA(a0,fEi[nt][0],accE[nt]);
        accE[nt] = MFMA(a1,fEi[nt][1],accE[nt]);
      }
      if (l < 16){
        #pragma unroll
        for (int nt = 0; nt < 4; ++nt){
          const int col = wq*64 + nt*16 + c16;
          #pragma unroll
          for (int e = 0; e < 4; ++e){
            const float v = accE[nt][e];
            gp[e][col] = (wq==2) ? ftanh(v) : fsig(v);
          }
        }
      }
    }
    BAR();
  }

  // ---- epilogue: F(255), prediction, BCE, loss reduce ----
  if (ch && l < 32){
    const float2 gi = *(const float2*)&gp[wv][2*l];
    const float2 gf = *(const float2*)&gp[wv][64+2*l];
    const float2 gg = *(const float2*)&gp[wv][128+2*l];
    const float2 go = *(const float2*)&gp[wv][192+2*l];
    cs0 = gf.x*cs0 + gi.x*gg.x;   cs1 = gf.y*cs1 + gi.y*gg.y;
    h0  = go.x*ftanh(cs0);        h1  = go.y*ftanh(cs1);

    float p = h0*ow0 + h1*ow1;
    p += __shfl_xor(p,16); p += __shfl_xor(p,8);
    p += __shfl_xor(p,4);  p += __shfl_xor(p,2); p += __shfl_xor(p,1);

    float lsum = la;   // nonzero only on l<16
    lsum += __shfl_xor(lsum,16); lsum += __shfl_xor(lsum,8);
    lsum += __shfl_xor(lsum,4);  lsum += __shfl_xor(lsum,2); lsum += __shfl_xor(lsum,1);

    if (l == 0){
      atomicAdd(xl_acc, lsum);
      const float y = p + out_b[0];
      predictions[b2] = fsig(y);
      const float lab = labels[b2];
      const float it  = is_train[b2];
      const float mx  = fmaxf(-y, 0.f);
      const float bce = y - y*lab + mx + __logf(__expf(-mx) + __expf(-y - mx));
      atomicAdd(bce_acc, bce * it);
    }
  }
}

// ---------------------------------------------------------------------------
// Kernel 3: finalize loss scalar
// ---------------------------------------------------------------------------
__global__ void final_kernel(const float* __restrict__ is_train,
                             const float* __restrict__ ws,
                             float* __restrict__ out){
  const int tid = threadIdx.x;
  __shared__ float red[256];
  red[tid] = is_train[tid] + is_train[tid+256] + is_train[tid+512] + is_train[tid+768];
  __syncthreads();
  for (int off = 128; off > 0; off >>= 1){
    if (tid < off) red[tid] += red[tid + off];
    __syncthreads();
  }
  if (tid == 0){
    const float yl = ws[1] / (red[0] + EPSF);
    out[0] = ws[0] / 256.0f + 0.1f * yl;
  }
}

extern "C" void kernel_launch(void* const* d_in, const int* in_sizes, int n_in,
                              void* d_out, int out_size, void* d_ws, size_t ws_size,
                              hipStream_t stream){
  const float* values   = (const float*)d_in[0];
  const float* masks    = (const float*)d_in[1];
  const float* deltas   = (const float*)d_in[2];
  const float* labels   = (const float*)d_in[5];
  const float* is_train = (const float*)d_in[6];
  const float* td_h_W   = (const float*)d_in[7];
  const float* td_h_b   = (const float*)d_in[8];
  const float* td_x_W   = (const float*)d_in[9];
  const float* td_x_b   = (const float*)d_in[10];
  const float* hist_W   = (const float*)d_in[11];
  const float* hist_b   = (const float*)d_in[12];
  const float* feat_W   = (const float*)d_in[13];
  const float* feat_b   = (const float*)d_in[14];
  const float* wc_W     = (const float*)d_in[15];
  const float* wc_b     = (const float*)d_in[16];
  const float* W_ih     = (const float*)d_in[17];
  const float* W_hh     = (const float*)d_in[18];
  const float* b_ih     = (const float*)d_in[19];
  const float* b_hh     = (const float*)d_in[20];
  const float* out_W    = (const float*)d_in[21];
  const float* out_b    = (const float*)d_in[22];

  float* out = (float*)d_out;                 // [0]=loss, [1..1025)=preds, [1025..)=imps
  float* ws  = (float*)d_ws;                  // [0]=xl_sum, [1]=bce_sum, [2..258)=msum

  hipMemsetAsync(ws, 0, 2*sizeof(float), stream);
  msum_kernel<<<256, 256, 0, stream>>>(masks, ws + 2);
  rits_kernel<<<256, 512, 0, stream>>>(values, masks, deltas, labels, is_train,
      td_h_W, td_h_b, td_x_W, td_x_b, hist_W, hist_b, feat_W, feat_b,
      wc_W, wc_b, W_ih, W_hh, b_ih, b_hh, out_W, out_b,
      ws + 2, ws + 0, ws + 1, out + 1, out + 1 + 1024);
  final_kernel<<<1, 256, 0, stream>>>(is_train, ws, out);
}

// Round 9
// 558.487 us; speedup vs baseline: 1.2822x; 1.2822x over previous
//
#include <hip/hip_runtime.h>

#define EPSF 1e-5f

typedef _Float16 h2f  __attribute__((ext_vector_type(2)));
typedef _Float16 h8   __attribute__((ext_vector_type(8)));
typedef float    f32x4 __attribute__((ext_vector_type(4)));

#if defined(__has_builtin)
#if __has_builtin(__builtin_amdgcn_fdot2)
#define HAVE_FDOT2 1
#endif
#endif

__device__ __forceinline__ float fsig(float x){ return 1.0f/(1.0f+__expf(-x)); }
__device__ __forceinline__ float ftanh(float x){
  float e = __expf(2.f*x);
  float r = (e-1.f)/(e+1.f);
  return (x > 15.f) ? 1.f : ((x < -15.f) ? -1.f : r);
}
// pack two f32 -> f16x2
__device__ __forceinline__ int pkf(float lo, float hi){
  return __builtin_bit_cast(int, __builtin_amdgcn_cvt_pkrtz(lo, hi));
}
// f16x2 dot with f32 accumulate (v_dot2_f32_f16)
__device__ __forceinline__ float dot2(int w, int x, float acc){
#ifdef HAVE_FDOT2
  return __builtin_amdgcn_fdot2(__builtin_bit_cast(h2f, w),
                                __builtin_bit_cast(h2f, x), acc, false);
#else
  h2f a = __builtin_bit_cast(h2f, w), b = __builtin_bit_cast(h2f, x);
  return acc + (float)a[0]*(float)b[0] + (float)a[1]*(float)b[1];
#endif
}
__device__ __forceinline__ int rl_i(int v, int l){ return __builtin_amdgcn_readlane(v, l); }
// light barrier: order LDS only; global loads/stores stay in flight
#define BAR() do{ asm volatile("s_waitcnt lgkmcnt(0)" ::: "memory"); __builtin_amdgcn_s_barrier(); }while(0)

// ---------------------------------------------------------------------------
// Kernel 1: msum[t] = sum_{b,n} masks[b,t,n] + EPS   (one block per t)
// ---------------------------------------------------------------------------
__global__ void msum_kernel(const float* __restrict__ masks, float* __restrict__ msum){
  const int t   = blockIdx.x;
  const int tid = threadIdx.x;
  const int b0  = tid >> 3;
  const int n4  = (tid & 7) << 2;
  float s = 0.f;
  #pragma unroll 4
  for (int i = 0; i < 32; ++i) {
    const int b = b0 + (i << 5);
    const float4 v = *reinterpret_cast<const float4*>(masks + ((size_t)b*256 + t)*32 + n4);
    s += v.x + v.y + v.z + v.w;
  }
  __shared__ float red[256];
  red[tid] = s; __syncthreads();
  for (int off = 128; off > 0; off >>= 1) {
    if (tid < off) red[tid] += red[tid + off];
    __syncthreads();
  }
  if (tid == 0) msum[t] = red[0] + EPSF;
}

// ---------------------------------------------------------------------------
// Kernel 2: persistent RNN. 512 blocks x 512 threads, 2 batch elems / block
// (2 blocks/CU -> cross-block phase overlap). Round-7 skeleton: chain waves
// cwb+e (cwb=(b&1)*2) run packed-f16 A-D; E phase = gate GEMM via 8x
// mfma_f32_16x16x32_f16 on all waves (A rows 0-1 = elems), weights in VGPRs.
// inp_s rows padded to 80 ints -> E A-fragment reads bank-conflict-free.
// ---------------------------------------------------------------------------
__global__ __launch_bounds__(512, 2) void rits_kernel(
  const float* __restrict__ values, const float* __restrict__ masks,
  const float* __restrict__ deltas, const float* __restrict__ labels,
  const float* __restrict__ is_train,
  const float* __restrict__ td_h_W, const float* __restrict__ td_h_b,
  const float* __restrict__ td_x_W, const float* __restrict__ td_x_b,
  const float* __restrict__ hist_W, const float* __restrict__ hist_b,
  const float* __restrict__ feat_W, const float* __restrict__ feat_b,
  const float* __restrict__ wc_W,  const float* __restrict__ wc_b,
  const float* __restrict__ W_ih,  const float* __restrict__ W_hh,
  const float* __restrict__ b_ih,  const float* __restrict__ b_hh,
  const float* __restrict__ out_W, const float* __restrict__ out_b,
  const float* __restrict__ msum,
  float* __restrict__ xl_acc, float* __restrict__ bce_acc,
  float* __restrict__ predictions, float* __restrict__ imps)
{
  // group-major packed chain weights (int4 = 4 packed pairs = 8 K-values)
  __shared__ __align__(16) int4 pkB[4][64];    // td_h_W row j, K=32
  __shared__ __align__(16) int4 pkC[8][32];    // hist_W row n, K=64
  __shared__ __align__(16) int4 pkDz[4][32];   // feat_W row n (diag 0), K=32
  __shared__ __align__(16) int4 pkDa[8][32];   // wc_W row n, K=64 ([gx|m])
  __shared__ __align__(16) int  inp_s[2][80];  // [e][ ccw 0..15 | mw 16..31 | hw 32..63 ]
                                               // (pad 80: rows on distinct bank halves)
  __shared__ float gp[2][256];                 // [elem][gate row]
  __shared__ float msum_l[256];                // 1/msum[t]

  const int tid = threadIdx.x;
  const int b   = blockIdx.x;
  const int wv  = tid >> 6;          // 0..7
  const int ln  = tid & 63;
  const int cwb = (b & 1) << 1;      // chain wave base: even blocks SIMD{0,1}, odd {2,3}
  const int me  = wv - cwb;          // my chain elem if in [0,2)
  const bool chain = (me == 0) | (me == 1);
  const int b2  = (b << 1) + (chain ? me : 0);

  // ---- stage packed chain weights + msum into LDS ----
  if (tid < 256){ const int g = tid >> 6, j = tid & 63;
    const float* w = td_h_W + j*32 + 8*g;
    pkB[g][j] = make_int4(pkf(w[0],w[1]), pkf(w[2],w[3]), pkf(w[4],w[5]), pkf(w[6],w[7])); }
  if (tid < 256){ const int g = tid >> 5, n = tid & 31;
    const float* w = hist_W + n*64 + 8*g;
    pkC[g][n] = make_int4(pkf(w[0],w[1]), pkf(w[2],w[3]), pkf(w[4],w[5]), pkf(w[6],w[7])); }
  if (tid < 128){ const int g = tid >> 5, n = tid & 31, c0 = 8*g;
    float v[8];
    #pragma unroll
    for (int k = 0; k < 8; ++k){ const int c = c0+k; v[k] = (c==n) ? 0.f : feat_W[n*32+c]; }
    pkDz[g][n] = make_int4(pkf(v[0],v[1]), pkf(v[2],v[3]), pkf(v[4],v[5]), pkf(v[6],v[7])); }
  if (tid < 256){ const int g = tid >> 5, n = tid & 31;
    const float* w = wc_W + n*64 + 8*g;
    pkDa[g][n] = make_int4(pkf(w[0],w[1]), pkf(w[2],w[3]), pkf(w[4],w[5]), pkf(w[6],w[7])); }
  if (tid < 256) msum_l[tid] = 1.0f / msum[tid];

  // ---- per-thread gate B-fragments: 2 n-tiles x 4 k-steps = 32 VGPRs ----
  // B[k][col] = W_cat[col][k]; lane holds col = wv*32 + nt*16 + (ln&15),
  // k = ks*32 + (ln>>4)*8 + 0..7 (packed pairs). k<64 -> W_ih, else W_hh.
  int4 Wb[2][4];
  const int kg = ln >> 4;
  #pragma unroll
  for (int nt = 0; nt < 2; ++nt){
    const int col = (wv << 5) + (nt << 4) + (ln & 15);
    #pragma unroll
    for (int ks = 0; ks < 4; ++ks){
      const int k0 = (ks << 5) + (kg << 3);
      const float* src = (k0 < 64) ? (W_ih + (size_t)col*64 + k0)
                                   : (W_hh + (size_t)col*64 + (k0 - 64));
      Wb[nt][ks] = make_int4(pkf(src[0],src[1]), pkf(src[2],src[3]),
                             pkf(src[4],src[5]), pkf(src[6],src[7]));
    }
  }
  // bias for my two output columns (C-in broadcast across rows)
  const int col0 = (wv << 5) + (ln & 15);
  const float bs0 = b_ih[col0]      + b_hh[col0];
  const float bs1 = b_ih[col0 + 16] + b_hh[col0 + 16];

  // ---- chain-wave registers ----
  float thb_r=0.f, tdxd_r=0.f, tdxb_r=0.f, histb_r=0.f, featb_r=0.f, wcb_r=0.f;
  float xv=0.f, mv=0.f, dv=0.f;
  if (chain){
    thb_r = td_h_b[ln];
    if (ln < 32){
      tdxd_r  = td_x_W[ln*33];
      tdxb_r  = td_x_b[ln];
      histb_r = hist_b[ln];
      featb_r = feat_b[ln];
      wcb_r   = wc_b[ln];
      const size_t base = (size_t)b2*8192 + ln;
      xv = values[base]; mv = masks[base]; dv = deltas[base];
    }
  }
  float h_reg = 0.f, c_reg = 0.f, loss_acc = 0.f;

  __syncthreads();

  for (int t = 0; t < 256; ++t){
    // ---- chain A-D (packed-f16 path) ----
    if (chain){
      const float x_cur = xv, m_cur = mv, d_cur = dv;
      float gx_r = 0.f;
      if (ln < 32){
        gx_r = __expf(-fmaxf(fmaf(d_cur, tdxd_r, tdxb_r), 0.f));
        if (t < 255){
          const size_t base = (size_t)b2*8192 + (size_t)(t+1)*32 + ln;
          xv = values[base]; mv = masks[base]; dv = deltas[base];
        }
      }
      const int i0 = (2*ln) & 63, i1 = (2*ln+1) & 63;
      const int dw = pkf(__shfl(d_cur, i0), __shfl(d_cur, i1));   // words 0..15 valid
      // B: gamma_h (64 rows, K=32); h *= gamma_h
      {
        float a0 = thb_r, a1 = 0.f;
        #pragma unroll
        for (int g4 = 0; g4 < 4; ++g4){
          const int4 w = pkB[g4][ln];
          a0 = dot2(w.x, rl_i(dw, 4*g4+0), a0);
          a1 = dot2(w.y, rl_i(dw, 4*g4+1), a1);
          a0 = dot2(w.z, rl_i(dw, 4*g4+2), a0);
          a1 = dot2(w.w, rl_i(dw, 4*g4+3), a1);
        }
        h_reg *= __expf(-fmaxf(a0+a1, 0.f));
      }
      const int hw = pkf(__shfl(h_reg, i0), __shfl(h_reg, i1));   // h pairs
      // C: x_h (32 rows, K=64); x_c
      float xh_v = 0.f, x_c_v = 0.f;
      if (ln < 32){
        float a0 = histb_r, a1 = 0.f, a2 = 0.f, a3 = 0.f;
        #pragma unroll
        for (int g4 = 0; g4 < 8; ++g4){
          const int4 w = pkC[g4][ln];
          a0 = dot2(w.x, rl_i(hw, 4*g4+0), a0);
          a1 = dot2(w.y, rl_i(hw, 4*g4+1), a1);
          a2 = dot2(w.z, rl_i(hw, 4*g4+2), a2);
          a3 = dot2(w.w, rl_i(hw, 4*g4+3), a3);
        }
        xh_v  = (a0+a1)+(a2+a3);
        x_c_v = m_cur*x_cur + (1.f-m_cur)*xh_v;
      }
      const int xcw = pkf(__shfl(x_c_v, i0), __shfl(x_c_v, i1));  // words 0..15
      const int j0 = (2*ln-32) & 63, j1 = (2*ln-31) & 63;
      const float ga  = __shfl(gx_r,  i0), gb  = __shfl(gx_r,  i1);
      const float ma_ = __shfl(m_cur, j0), mb_ = __shfl(m_cur, j1);
      const int aw = (ln < 16) ? pkf(ga, gb) : pkf(ma_, mb_);     // gx|m pairs
      // D: z_h, alpha, c_h, c_c, loss, imputation
      float ccv = 0.f;
      if (ln < 32){
        float z0 = featb_r, z1 = 0.f;
        #pragma unroll
        for (int g4 = 0; g4 < 4; ++g4){
          const int4 w = pkDz[g4][ln];
          z0 = dot2(w.x, rl_i(xcw, 4*g4+0), z0);
          z1 = dot2(w.y, rl_i(xcw, 4*g4+1), z1);
          z0 = dot2(w.z, rl_i(xcw, 4*g4+2), z0);
          z1 = dot2(w.w, rl_i(xcw, 4*g4+3), z1);
        }
        const float z = z0 + z1;
        float a0 = wcb_r, a1 = 0.f, a2 = 0.f, a3 = 0.f;
        #pragma unroll
        for (int g4 = 0; g4 < 8; ++g4){
          const int4 w = pkDa[g4][ln];
          a0 = dot2(w.x, rl_i(aw, 4*g4+0), a0);
          a1 = dot2(w.y, rl_i(aw, 4*g4+1), a1);
          a2 = dot2(w.z, rl_i(aw, 4*g4+2), a2);
          a3 = dot2(w.w, rl_i(aw, 4*g4+3), a3);
        }
        const float al = (a0+a1)+(a2+a3);
        const float ch = al*z + (1.f-al)*xh_v;
        loss_acc += (fabsf(x_cur-xh_v)+fabsf(x_cur-z)+fabsf(x_cur-ch))*m_cur*msum_l[t];
        ccv = m_cur*x_cur + (1.f-m_cur)*ch;
        imps[(size_t)b2*8192 + (size_t)t*32 + ln] = ccv;
      }
      const int ccw = pkf(__shfl(ccv, i0), __shfl(ccv, i1));      // words 0..15
      inp_s[me][ln] = (ln < 16) ? ccw : (ln < 32 ? aw : hw);
    }

    BAR();   // inp_s visible to all waves

    // ---- E: gate GEMM via MFMA; A rows = elems 0-1, rows 2-15 zero ----
    {
      const int arow = ln & 15;
      int4 A[4];
      if (arow < 2){
        #pragma unroll
        for (int ks = 0; ks < 4; ++ks)
          A[ks] = *reinterpret_cast<const int4*>(&inp_s[arow][(ks << 4) + (kg << 2)]);
      } else {
        #pragma unroll
        for (int ks = 0; ks < 4; ++ks) A[ks] = make_int4(0,0,0,0);
      }
      f32x4 acc0 = {bs0, bs0, bs0, bs0};
      f32x4 acc1 = {bs1, bs1, bs1, bs1};
      #pragma unroll
      for (int ks = 0; ks < 4; ++ks){
        acc0 = __builtin_amdgcn_mfma_f32_16x16x32_f16(
                 __builtin_bit_cast(h8, A[ks]), __builtin_bit_cast(h8, Wb[0][ks]), acc0, 0,0,0);
        acc1 = __builtin_amdgcn_mfma_f32_16x16x32_f16(
                 __builtin_bit_cast(h8, A[ks]), __builtin_bit_cast(h8, Wb[1][ks]), acc1, 0,0,0);
      }
      // C/D: col=lane&15, row=(lane>>4)*4+reg -> kg==0 lanes hold rows 0-3
      if (kg == 0){
        #pragma unroll
        for (int e = 0; e < 2; ++e){
          gp[e][col0]      = acc0[e];
          gp[e][col0 + 16] = acc1[e];
        }
      }
    }

    BAR();   // gates visible to chain waves

    // ---- F: LSTM pointwise update (chain waves) ----
    if (chain){
      const float ig = gp[me][ln];
      const float fg = gp[me][64+ln];
      const float gg = gp[me][128+ln];
      const float og = gp[me][192+ln];
      c_reg = fsig(fg)*c_reg + fsig(ig)*ftanh(gg);
      h_reg = fsig(og)*ftanh(c_reg);
    }
  }

  // ---- epilogue: loss reduce + prediction/BCE (chain waves) ----
  if (chain){
    float l = loss_acc;   // nonzero only on ln<32
    l += __shfl_xor(l,16); l += __shfl_xor(l,8);
    l += __shfl_xor(l,4);  l += __shfl_xor(l,2); l += __shfl_xor(l,1);
    if (ln == 0) atomicAdd(xl_acc, l);

    float p = h_reg * out_W[ln];
    p += __shfl_xor(p,32); p += __shfl_xor(p,16); p += __shfl_xor(p,8);
    p += __shfl_xor(p,4);  p += __shfl_xor(p,2);  p += __shfl_xor(p,1);
    if (ln == 0){
      const float y = p + out_b[0];
      predictions[b2] = fsig(y);
      const float lab = labels[b2];
      const float it  = is_train[b2];
      const float mx  = fmaxf(-y, 0.f);
      const float bce = y - y*lab + mx + __logf(__expf(-mx) + __expf(-y - mx));
      atomicAdd(bce_acc, bce * it);
    }
  }
}

// ---------------------------------------------------------------------------
// Kernel 3: finalize loss scalar
// ---------------------------------------------------------------------------
__global__ void final_kernel(const float* __restrict__ is_train,
                             const float* __restrict__ ws,
                             float* __restrict__ out){
  const int tid = threadIdx.x;
  __shared__ float red[256];
  red[tid] = is_train[tid] + is_train[tid+256] + is_train[tid+512] + is_train[tid+768];
  __syncthreads();
  for (int off = 128; off > 0; off >>= 1){
    if (tid < off) red[tid] += red[tid + off];
    __syncthreads();
  }
  if (tid == 0){
    const float yl = ws[1] / (red[0] + EPSF);
    out[0] = ws[0] / 256.0f + 0.1f * yl;
  }
}

extern "C" void kernel_launch(void* const* d_in, const int* in_sizes, int n_in,
                              void* d_out, int out_size, void* d_ws, size_t ws_size,
                              hipStream_t stream){
  const float* values   = (const float*)d_in[0];
  const float* masks    = (const float*)d_in[1];
  const float* deltas   = (const float*)d_in[2];
  const float* labels   = (const float*)d_in[5];
  const float* is_train = (const float*)d_in[6];
  const float* td_h_W   = (const float*)d_in[7];
  const float* td_h_b   = (const float*)d_in[8];
  const float* td_x_W   = (const float*)d_in[9];
  const float* td_x_b   = (const float*)d_in[10];
  const float* hist_W   = (const float*)d_in[11];
  const float* hist_b   = (const float*)d_in[12];
  const float* feat_W   = (const float*)d_in[13];
  const float* feat_b   = (const float*)d_in[14];
  const float* wc_W     = (const float*)d_in[15];
  const float* wc_b     = (const float*)d_in[16];
  const float* W_ih     = (const float*)d_in[17];
  const float* W_hh     = (const float*)d_in[18];
  const float* b_ih     = (const float*)d_in[19];
  const float* b_hh     = (const float*)d_in[20];
  const float* out_W    = (const float*)d_in[21];
  const float* out_b    = (const float*)d_in[22];

  float* out = (float*)d_out;                 // [0]=loss, [1..1025)=preds, [1025..)=imps
  float* ws  = (float*)d_ws;                  // [0]=xl_sum, [1]=bce_sum, [2..258)=msum

  hipMemsetAsync(ws, 0, 2*sizeof(float), stream);
  msum_kernel<<<256, 256, 0, stream>>>(masks, ws + 2);
  rits_kernel<<<512, 512, 0, stream>>>(values, masks, deltas, labels, is_train,
      td_h_W, td_h_b, td_x_W, td_x_b, hist_W, hist_b, feat_W, feat_b,
      wc_W, wc_b, W_ih, W_hh, b_ih, b_hh, out_W, out_b,
      ws + 2, ws + 0, ws + 1, out + 1, out + 1 + 1024);
  final_kernel<<<1, 256, 0, stream>>>(is_train, ws, out);
}